// Round 3
// baseline (490.239 us; speedup 1.0000x reference)
//
#include <hip/hip_runtime.h>
#include <math.h>

// Problem constants (reference: VOCAB=10000, HID=256, B=64, T=64)
#define VOCABN 10000
#define HIDN   256
#define GATES  1024   // 4*HID
#define BN     64
#define TN     64
#define BT     4096   // B*T
#define NCT    625    // vocab col-tiles of 16 (10000 = 625*16 exactly)

// k_plstm zero-exchange geometry
#define HPITCH 264    // h LDS row pitch (bf16 elems): 264%... breaks bank aliasing
#define HBUFE  4224   // 16 rows * 264 = one h buffer, u16 elems
#define WLDS_B 131072 // 128 KB LDS-resident W_h (4 waves x 4 ct x 8 KB)
#define SMEMSZ (WLDS_B + 2 * HBUFE * 2)   // 147968 B

typedef unsigned int       u32;
typedef unsigned short     u16;
typedef unsigned long long u64;
typedef float v4f __attribute__((ext_vector_type(4)));
typedef short v8s __attribute__((ext_vector_type(8)));

__device__ __forceinline__ float bf2f(u16 u) {
    return __uint_as_float(((u32)u) << 16);
}
__device__ __forceinline__ u16 f2bf(float f) {          // round-to-nearest-even
    u32 u = __float_as_uint(f);
    u += 0x7FFFu + ((u >> 16) & 1u);
    return (u16)(u >> 16);
}
__device__ __forceinline__ float fast_sigmoid(float x) {
    return 1.0f / (1.0f + __expf(-x));
}
__device__ __forceinline__ float fast_tanh(float x) {
    float e = __expf(-2.0f * fabsf(x));
    float t = (1.0f - e) / (1.0f + e);
    return copysignf(t, x);
}

// ---------------------------------------------------------------------------
// fp32 [HIDN][ncols] tile c -> bf16 MFMA B-fragment layout [c][8 q][64 l][8].
// Fragment (c,q), lane l holds B[k = q*32 + (l>>4)*8 + j][n = c*16 + (l&15)].
// ---------------------------------------------------------------------------
__device__ __forceinline__ void wfrag_dev(
    const float* __restrict__ src, u16* __restrict__ dst, int ncols, int c,
    int t, u16 lt[HIDN][16])
{
    const float* s = src + (size_t)t * ncols + c * 16;
    #pragma unroll
    for (int j4 = 0; j4 < 4; ++j4) {
        float4 v = *(const float4*)(s + j4 * 4);
        lt[t][j4*4+0] = f2bf(v.x);
        lt[t][j4*4+1] = f2bf(v.y);
        lt[t][j4*4+2] = f2bf(v.z);
        lt[t][j4*4+3] = f2bf(v.w);
    }
    __syncthreads();
    #pragma unroll
    for (int h = 0; h < 2; ++h) {
        int f = t + h * 256;             // frag id = q*64 + l
        int q = f >> 6, l = f & 63;
        int m = l & 15, kb = q * 32 + ((l >> 4) & 3) * 8;
        u32 w[4];
        #pragma unroll
        for (int j = 0; j < 4; ++j)
            w[j] = (u32)lt[kb + 2*j][m] | ((u32)lt[kb + 2*j + 1][m] << 16);
        *(uint4*)(dst + (((size_t)c * 8 + q) * 64 + l) * 8) =
            make_uint4(w[0], w[1], w[2], w[3]);
    }
}

// ---------------------------------------------------------------------------
// wfrag for both W_lstm halves (128 blocks) — fallback-path prep.
// ---------------------------------------------------------------------------
__global__ __launch_bounds__(256) void k_wfrag2(
    const float* __restrict__ W_lstm,
    u16* __restrict__ Wxf, u16* __restrict__ Whf)
{
    __shared__ u16 lt[HIDN][16];
    const int bid = blockIdx.x;
    if (bid < 64)
        wfrag_dev(W_lstm, Wxf, GATES, bid, threadIdx.x, lt);
    else
        wfrag_dev(W_lstm + (size_t)HIDN * GATES, Whf, GATES, bid - 64,
                  threadIdx.x, lt);
}

// ---------------------------------------------------------------------------
// ALL THREE weight transforms in one launch (753 blocks) — wide-ws path.
// ---------------------------------------------------------------------------
__global__ __launch_bounds__(256) void k_wfrag3(
    const float* __restrict__ W_lstm,
    const float* __restrict__ W_dense,
    u16* __restrict__ Wxf, u16* __restrict__ Whf, u16* __restrict__ Wf)
{
    __shared__ u16 lt[HIDN][16];
    const int bid = blockIdx.x;
    if (bid < 64)
        wfrag_dev(W_lstm, Wxf, GATES, bid, threadIdx.x, lt);
    else if (bid < 128)
        wfrag_dev(W_lstm + (size_t)HIDN * GATES, Whf, GATES, bid - 64,
                  threadIdx.x, lt);
    else
        wfrag_dev(W_dense, Wf, VOCABN, bid - 128, threadIdx.x, lt);
}

// ---------------------------------------------------------------------------
// wfrag for W_dense (625 blocks) — fallback path, runs AFTER plstm (Wf
// aliases gx2 there).
// ---------------------------------------------------------------------------
__global__ __launch_bounds__(256) void k_wfrag(
    const float* __restrict__ src,   // [HIDN][ncols]
    u16*         __restrict__ dst,   // [nct][8][64][8]
    int ncols)
{
    __shared__ u16 lt[HIDN][16];
    wfrag_dev(src, dst, ncols, blockIdx.x, threadIdx.x, lt);
}

// ---------------------------------------------------------------------------
// Kernel 1 (MFMA): gates_x = E[idx] @ W_x + b_lstm, written PERMUTED+bf16 for
// the zero-exchange k_plstm. 256 blocks = (t 0..63) x (rg 0..3); block covers
// batch rows rg*16..+15 at time t (A-frag row m <-> b = rg*16+m).
// Output gx2 u64 layout: [((t*4+rg)*4 + w')*64 + lane][slot = gg*4 + gamma],
// one u64 = 4 bf16 gate values for b-offsets r=0..3 (kq*4+r rows).
// Writer lane == consumer lane (both quad*16+m); w' = (c&15)>>2, gg = c&3,
// gamma = c>>4 for gate column-tile c. Bias b_lstm folded in here.
// ---------------------------------------------------------------------------
__global__ __launch_bounds__(256) void k_xgates(
    const int*   __restrict__ idx,   // [BT] = [B][T]
    const float* __restrict__ E,     // [VOCAB][HIDN]
    const u16*   __restrict__ Wxf,   // [64][8][64][8]
    const float* __restrict__ bl,    // [GATES]
    u64*         __restrict__ gx2)   // [64*4*4*64*16] u64 (8 MB)
{
    const int bid = blockIdx.x;
    const int t   = bid >> 2, rg = bid & 3;
    const int tid = threadIdx.x;
    const int w   = tid >> 6, lane = tid & 63;
    const int m   = lane & 15, quad = lane >> 4;

    v8s a[8];
    {
        const float* e = E + (size_t)idx[(rg * 16 + m) * TN + t] * HIDN
                         + quad * 8;
        #pragma unroll
        for (int q = 0; q < 8; ++q) {
            float4 x0 = *(const float4*)(e + q * 32);
            float4 x1 = *(const float4*)(e + q * 32 + 4);
            uint4 t4 = make_uint4(
                (u32)f2bf(x0.x) | ((u32)f2bf(x0.y) << 16),
                (u32)f2bf(x0.z) | ((u32)f2bf(x0.w) << 16),
                (u32)f2bf(x1.x) | ((u32)f2bf(x1.y) << 16),
                (u32)f2bf(x1.z) | ((u32)f2bf(x1.w) << 16));
            a[q] = *(v8s*)&t4;
        }
    }

    for (int i = 0; i < 16; ++i) {
        const int c = 4 * i + w;          // col-tile, c%4 == w
        v4f acc = {0.f, 0.f, 0.f, 0.f};
        #pragma unroll
        for (int q = 0; q < 8; ++q) {
            v8s b = *(const v8s*)(Wxf + (((size_t)c * 8 + q) * 64 + lane) * 8);
            acc = __builtin_amdgcn_mfma_f32_16x16x32_bf16(a[q], b, acc, 0, 0, 0);
        }
        const float bv = bl[c * 16 + m];
        u32 lo = (u32)f2bf(acc[0] + bv) | ((u32)f2bf(acc[1] + bv) << 16);
        u32 hi = (u32)f2bf(acc[2] + bv) | ((u32)f2bf(acc[3] + bv) << 16);
        u64 pk = (u64)lo | ((u64)hi << 32);
        const size_t di =
            ((((size_t)t * 4 + rg) * 4 + ((c & 15) >> 2)) * 64 + lane) * 16
            + (c & 3) * 4 + (c >> 4);
        gx2[di] = pk;
    }
}

// ---------------------------------------------------------------------------
// Kernel 2: ZERO-EXCHANGE persistent LSTM. 4 blocks x 256 thr (1 wave/SIMD),
// each block owns 16 batch rows and evolves ALL 256 units for 64 steps with
// no inter-block communication (the R0-R2 LLC exchange chains are gone).
//
// On-chip W_h per block (512 KB total):
//  * registers: 384 KB — wave w holds groups G = 4w+gg (gg=0..2), i.e. cts
//    {G, 16+G, 32+G, 48+G} x 8 q-frags = 96 v8s = 384 VGPR/lane.
//  * LDS: 128 KB — group G = 4w+3 per wave (32 frags x 1 KB x 4 waves).
// Group assignment puts i,j,f,o of unit G*16+m in the SAME lane's accs
// (D-layout is ct-independent) -> cell update fully in-register.
//
// h(t) -> A-frag transpose via LDS double buffer (pitch 264 bf16: b128 reads
// land 8 lanes per 4-bank group = conflict-free). One light barrier per step
// (lgkmcnt(0) + raw s_barrier; no vmcnt drain, so gx2 prefetch and Hb stores
// stay in flight across steps).
//
// gx2 (x-gates, bf16-packed by k_xgates in this lane's exact layout): 16 u64
// per lane per step; quarter gg is refilled for t+1 right after cell(t,gg)
// consumes it (no double buffer, full-step latency window).
// ---------------------------------------------------------------------------
__global__ __launch_bounds__(256, 1) void k_plstm(
    const u16*   __restrict__ Whf,   // [64 ct][8 q][64 l][8] h-part frags
    const u64*   __restrict__ gx2,   // packed x-gates (see k_xgates)
    u16*         __restrict__ Hb)    // [BT][HIDN] bf16 output
{
    extern __shared__ char smem[];
    u16* WgL   = (u16*)smem;                 // [w][gm][q][lane][8] u16
    u16* hbufu = (u16*)(smem + WLDS_B);      // [2][16][HPITCH] u16

    const int tid  = threadIdx.x;
    const int rg   = blockIdx.x;             // 0..3: batch rows rg*16..+15
    const int w    = tid >> 6;
    const int lane = tid & 63;
    const int m    = lane & 15, kq = lane >> 4;

    // ---- prologue: weights into registers + LDS, zero h buffer, gx t=0 ----
    v8s wr[3][4][8];
    #pragma unroll
    for (int gg = 0; gg < 3; ++gg)
        #pragma unroll
        for (int gm = 0; gm < 4; ++gm)
            #pragma unroll
            for (int q = 0; q < 8; ++q)
                wr[gg][gm][q] = *(const v8s*)(
                    Whf + (((size_t)(gm * 16 + 4 * w + gg) * 8 + q) * 64
                           + lane) * 8);

    #pragma unroll
    for (int gm = 0; gm < 4; ++gm)
        #pragma unroll
        for (int q = 0; q < 8; ++q)
            *(uint4*)(WgL + ((w * 32 + gm * 8 + q) * 64 + lane) * 8) =
                *(const uint4*)(
                    Whf + (((size_t)(gm * 16 + 4 * w + 3) * 8 + q) * 64
                           + lane) * 8);

    {   // zero both h buffers (t=0 reads buffer 0 as h(-1)=0)
        u32* hz = (u32*)hbufu;
        for (int i = tid; i < HBUFE; i += 256) hz[i] = 0u;
    }

    u64 gb[16];
    {
        const u64* g0 = gx2 + (((size_t)0 * 4 + rg) * 4 + w) * 64 * 16
                        + (size_t)lane * 16;
        #pragma unroll
        for (int s = 0; s < 16; ++s) gb[s] = g0[s];
    }

    float cs[16];
    #pragma unroll
    for (int i = 0; i < 16; ++i) cs[i] = 0.0f;

    __syncthreads();

    // ---- cell update for group GG given 4 gate accs (i,j,f,o) ----
    // gb slot gg*4+gamma holds 4 bf16 (r=0..3) of the x-part (+bias).
    #define CELL(GG, E0, E1, E2, E3)                                          \
    {                                                                         \
        _Pragma("unroll")                                                     \
        for (int r = 0; r < 4; ++r) {                                         \
            float xi = bf2f((u16)(gb[(GG)*4 + 0] >> (16 * r)));               \
            float xj = bf2f((u16)(gb[(GG)*4 + 1] >> (16 * r)));               \
            float xf = bf2f((u16)(gb[(GG)*4 + 2] >> (16 * r)));               \
            float xo = bf2f((u16)(gb[(GG)*4 + 3] >> (16 * r)));               \
            float ig = fast_sigmoid(E0[r] + xi);                              \
            float jt = fast_tanh   (E1[r] + xj);                              \
            float fg = fast_sigmoid(E2[r] + xf + 1.0f);                       \
            float og = fast_sigmoid(E3[r] + xo);                              \
            float cn = fg * cs[(GG)*4 + r] + ig * jt;                         \
            cs[(GG)*4 + r] = cn;                                              \
            u16 hv = f2bf(og * fast_tanh(cn));                                \
            hwr[(kq * 4 + r) * HPITCH + (4 * w + (GG)) * 16 + m] = hv;        \
            Hb[((size_t)(rg * 16 + kq * 4 + r) * TN + t) * HIDN              \
               + (4 * w + (GG)) * 16 + m] = hv;                               \
        }                                                                     \
    }

    #define PREFETCH_G(GG)                                                    \
    if (t + 1 < TN) {                                                         \
        const u64* gp = gx2 + ((((size_t)(t + 1) * 4 + rg) * 4 + w) * 64      \
                               + lane) * 16 + (GG) * 4;                       \
        gb[(GG)*4 + 0] = gp[0]; gb[(GG)*4 + 1] = gp[1];                       \
        gb[(GG)*4 + 2] = gp[2]; gb[(GG)*4 + 3] = gp[3];                       \
    }

    for (int t = 0; t < TN; ++t) {
        const u16* hrd = hbufu + (t & 1) * HBUFE;
        u16*       hwr = hbufu + ((t + 1) & 1) * HBUFE;

        // a-frags: A[row=m][k = q*32 + kq*8 + j] from h(t-1)
        v8s a[8];
        #pragma unroll
        for (int q = 0; q < 8; ++q)
            a[q] = *(const v8s*)(hrd + m * HPITCH + q * 32 + kq * 8);

        // ---- register weight groups ----
        #pragma unroll
        for (int gg = 0; gg < 3; ++gg) {
            v4f e0 = {0.f,0.f,0.f,0.f}, e1 = {0.f,0.f,0.f,0.f};
            v4f e2 = {0.f,0.f,0.f,0.f}, e3 = {0.f,0.f,0.f,0.f};
            #pragma unroll
            for (int q = 0; q < 8; ++q) {
                e0 = __builtin_amdgcn_mfma_f32_16x16x32_bf16(a[q], wr[gg][0][q], e0, 0, 0, 0);
                e1 = __builtin_amdgcn_mfma_f32_16x16x32_bf16(a[q], wr[gg][1][q], e1, 0, 0, 0);
                e2 = __builtin_amdgcn_mfma_f32_16x16x32_bf16(a[q], wr[gg][2][q], e2, 0, 0, 0);
                e3 = __builtin_amdgcn_mfma_f32_16x16x32_bf16(a[q], wr[gg][3][q], e3, 0, 0, 0);
            }
            CELL(gg, e0, e1, e2, e3)
            PREFETCH_G(gg)
        }

        // ---- LDS weight group (G = 4w+3) ----
        {
            const u16* wl = WgL + w * 16384;
            v4f e0 = {0.f,0.f,0.f,0.f}, e1 = {0.f,0.f,0.f,0.f};
            v4f e2 = {0.f,0.f,0.f,0.f}, e3 = {0.f,0.f,0.f,0.f};
            #pragma unroll
            for (int q = 0; q < 8; ++q) {
                v8s b0 = *(const v8s*)(wl + ((0 * 8 + q) * 64 + lane) * 8);
                v8s b1 = *(const v8s*)(wl + ((1 * 8 + q) * 64 + lane) * 8);
                v8s b2 = *(const v8s*)(wl + ((2 * 8 + q) * 64 + lane) * 8);
                v8s b3 = *(const v8s*)(wl + ((3 * 8 + q) * 64 + lane) * 8);
                e0 = __builtin_amdgcn_mfma_f32_16x16x32_bf16(a[q], b0, e0, 0, 0, 0);
                e1 = __builtin_amdgcn_mfma_f32_16x16x32_bf16(a[q], b1, e1, 0, 0, 0);
                e2 = __builtin_amdgcn_mfma_f32_16x16x32_bf16(a[q], b2, e2, 0, 0, 0);
                e3 = __builtin_amdgcn_mfma_f32_16x16x32_bf16(a[q], b3, e3, 0, 0, 0);
            }
            CELL(3, e0, e1, e2, e3)
            PREFETCH_G(3)
        }

        // light barrier: drain LDS ops only (keep gx2/Hb vmem in flight)
        asm volatile("s_waitcnt lgkmcnt(0)" ::: "memory");
        __builtin_amdgcn_s_barrier();
    }
    #undef CELL
    #undef PREFETCH_G
}

// ---------------------------------------------------------------------------
// Kernel 3 (MFMA dense, 8-way vocab split — R14 verbatim): 512 blocks =
// 64 row-groups(64 rows, 4 register-resident a-frag row-tiles) x 8 vocab
// eighths (~640 KB Wf each, L2-resident per XCD under round-robin %8).
// ---------------------------------------------------------------------------
__global__ __launch_bounds__(256, 1) void k_dense(
    const u16*   __restrict__ Hb,    // [BT][HIDN] bf16
    const u16*   __restrict__ Wf,    // [625][8][64][8]
    const float* __restrict__ bd,    // [VOCAB]
    float*       __restrict__ S)     // [8][BT] partial sumexp
{
    __shared__ float Sl[64];
    const int bid = blockIdx.x;
    const int hv  = bid & 7;                    // vocab eighth (XCD-aligned)
    const int rg  = bid >> 3;                   // 0..63
    const int r0  = rg * 64;
    const int tid = threadIdx.x;
    const int w   = tid >> 6, lane = tid & 63;
    const int m   = lane & 15, kq = lane >> 4;

    if (tid < 64) Sl[tid] = 0.0f;

    v8s a[4][8];
    #pragma unroll
    for (int rt = 0; rt < 4; ++rt) {
        const u16* hrow = Hb + (size_t)(r0 + rt * 16 + m) * HIDN + kq * 8;
        #pragma unroll
        for (int q = 0; q < 8; ++q)
            a[rt][q] = *(const v8s*)(hrow + q * 32);
    }
    __syncthreads();

    float s[4][4] = {{0.f,0.f,0.f,0.f},{0.f,0.f,0.f,0.f},
                     {0.f,0.f,0.f,0.f},{0.f,0.f,0.f,0.f}};
    const int cbeg = (hv * NCT) >> 3;
    const int cend = ((hv + 1) * NCT) >> 3;
    for (int c = cbeg + w; c < cend; c += 4) {
        v4f acc[4] = {{0.f,0.f,0.f,0.f},{0.f,0.f,0.f,0.f},
                      {0.f,0.f,0.f,0.f},{0.f,0.f,0.f,0.f}};
        #pragma unroll
        for (int q = 0; q < 8; ++q) {
            v8s bq = *(const v8s*)(Wf + (((size_t)c * 8 + q) * 64 + lane) * 8);
            #pragma unroll
            for (int rt = 0; rt < 4; ++rt)
                acc[rt] = __builtin_amdgcn_mfma_f32_16x16x32_bf16(
                              a[rt][q], bq, acc[rt], 0, 0, 0);
        }
        const float bv = bd[c * 16 + m];
        #pragma unroll
        for (int rt = 0; rt < 4; ++rt)
            #pragma unroll
            for (int r = 0; r < 4; ++r)
                s[rt][r] += __expf(acc[rt][r] + bv);
    }

    #pragma unroll
    for (int rt = 0; rt < 4; ++rt)
        #pragma unroll
        for (int r = 0; r < 4; ++r)
            atomicAdd(&Sl[rt * 16 + kq * 4 + r], s[rt][r]);
    __syncthreads();
    if (tid < 64) S[(size_t)hv * BT + r0 + tid] = Sl[tid];
}

// ---------------------------------------------------------------------------
// Kernel 4 (target + final fused — R14 verbatim): per row, dot h with the
// target's W column (32 thr/row), then ppl = exp(log(sum S) - logit).
// ---------------------------------------------------------------------------
__global__ __launch_bounds__(256) void k_target(
    const u16*   __restrict__ Hb,
    const u16*   __restrict__ Wf,
    const float* __restrict__ bd,
    const int*   __restrict__ tgt,
    const float* __restrict__ S,     // [8][BT]
    float*       __restrict__ out)   // [BT]
{
    const int tid = threadIdx.x;
    const int row = blockIdx.x * 8 + (tid >> 5);
    const int t   = tid & 31;
    const int q   = t >> 2, lq = t & 3;
    const int v   = tgt[row];
    const int c   = v >> 4, vm = v & 15;
    const int kb  = q * 32 + lq * 8;

    v8s h  = *(const v8s*)(Hb + (size_t)row * HIDN + kb);
    v8s wv = *(const v8s*)(Wf + (((size_t)c * 8 + q) * 64 + lq * 16 + vm) * 8);
    float acc = 0.0f;
    #pragma unroll
    for (int j = 0; j < 8; ++j)
        acc = fmaf(bf2f((u16)h[j]), bf2f((u16)wv[j]), acc);
    #pragma unroll
    for (int off = 16; off >= 1; off >>= 1)
        acc += __shfl_down(acc, off, 32);
    if (t == 0) {
        float tlv = acc + bd[v];
        float sum = 0.0f;
        #pragma unroll
        for (int p = 0; p < 8; ++p) sum += S[(size_t)p * BT + row];
        out[row] = __expf(__logf(sum) - tlv);
    }
}

// ---------------------------------------------------------------------------
extern "C" void kernel_launch(void* const* d_in, const int* in_sizes, int n_in,
                              void* d_out, int out_size, void* d_ws, size_t ws_size,
                              hipStream_t stream) {
    const int*   input   = (const int*)  d_in[0];   // [B,T]
    const int*   targets = (const int*)  d_in[1];   // [B,T]
    const float* E       = (const float*)d_in[2];   // [VOCAB,HID]
    const float* W_lstm  = (const float*)d_in[3];   // [2H,4H]
    const float* b_lstm  = (const float*)d_in[4];   // [4H]
    const float* W_dense = (const float*)d_in[5];   // [HID,VOCAB]
    const float* b_dense = (const float*)d_in[6];   // [VOCAB]
    float* out = (float*)d_out;                     // [B,T] perplexity

    static bool attr_done = false;
    if (!attr_done) {
        hipFuncSetAttribute((const void*)k_plstm,
                            hipFuncAttributeMaxDynamicSharedMemorySize,
                            SMEMSZ);
        attr_done = true;
    }

    char* ws = (char*)d_ws;
    const bool wide = (ws_size >= ((size_t)25 << 20));

    if (wide) {
        // 5-node layout:
        //  [0,8M): gx2 | [16M,21.12M): Wf | [21.25M,23.25M): Hb
        //  [23.25M,+512K): Whf | [23.75M,+512K): Wxf
        //  [24.25M+128K,+128K): S
        u64*   gx2 = (u64*)ws;
        u16*   Wf  = (u16*)(ws + ((size_t)16 << 20));
        u16*   Hb  = (u16*)(ws + ((size_t)21 << 20) + ((size_t)256 << 10));
        u16*   Whf = (u16*)(ws + ((size_t)23 << 20) + ((size_t)256 << 10));
        u16*   Wxf = (u16*)(ws + ((size_t)23 << 20) + ((size_t)768 << 10));
        float* S   = (float*)(ws + ((size_t)24 << 20) + ((size_t)384 << 10));

        k_wfrag3<<<753,     256, 0, stream>>>(W_lstm, W_dense, Wxf, Whf, Wf);
        k_xgates<<<BT / 16, 256, 0, stream>>>(input, E, Wxf, b_lstm, gx2);
        k_plstm <<<4,       256, SMEMSZ, stream>>>(Whf, gx2, Hb);
        k_dense <<<512,     256, 0, stream>>>(Hb, Wf, b_dense, S);
        k_target<<<BT / 8,  256, 0, stream>>>(Hb, Wf, b_dense, targets, S, out);
    } else {
        // 6-node fallback (Wf aliases gx2 after plstm).
        //  [0,8M): gx2/Wf | [16M,18M): Hb | [18M,+512K): Whf
        //  [18.5M,+512K): Wxf | [19M+128K,+128K): S
        u64*   gx2 = (u64*)ws;
        u16*   Wf  = (u16*)ws;
        u16*   Hb  = (u16*)(ws + ((size_t)16 << 20));
        u16*   Whf = (u16*)(ws + ((size_t)18 << 20));
        u16*   Wxf = (u16*)(ws + ((size_t)18 << 20) + ((size_t)512 << 10));
        float* S   = (float*)(ws + ((size_t)19 << 20) + ((size_t)128 << 10));

        k_wfrag2<<<128,     256, 0, stream>>>(W_lstm, Wxf, Whf);
        k_xgates<<<BT / 16, 256, 0, stream>>>(input, E, Wxf, b_lstm, gx2);
        k_plstm <<<4,       256, SMEMSZ, stream>>>(Whf, gx2, Hb);
        k_wfrag <<<NCT,     256, 0, stream>>>(W_dense, Wf, VOCABN);
        k_dense <<<512,     256, 0, stream>>>(Hb, Wf, b_dense, S);
        k_target<<<BT / 8,  256, 0, stream>>>(Hb, Wf, b_dense, targets, S, out);
    }
}

// Round 4
// 388.077 us; speedup vs baseline: 1.2633x; 1.2633x over previous
//
#include <hip/hip_runtime.h>
#include <math.h>

// Problem constants (reference: VOCAB=10000, HID=256, B=64, T=64)
#define VOCABN 10000
#define HIDN   256
#define GATES  1024   // 4*HID
#define BN     64
#define TN     64
#define BT     4096   // B*T
#define NCT    625    // vocab col-tiles of 16 (10000 = 625*16 exactly)

// k_plstm zero-exchange geometry (8-wave re-tile)
#define HPITCH 264    // h LDS row pitch (bf16 elems) — breaks bank aliasing
#define HBUFE  4224   // 16 rows * 264 = one h buffer, u16 elems
#define WLDS_B 131072 // 128 KB LDS-resident W_h (8 waves x 16 frags x 1 KB)
#define SMEMSZ (WLDS_B + 2 * HBUFE * 2)   // 147968 B

typedef unsigned int       u32;
typedef unsigned short     u16;
typedef unsigned long long u64;
typedef float v4f __attribute__((ext_vector_type(4)));
typedef short v8s __attribute__((ext_vector_type(8)));

__device__ __forceinline__ float bf2f(u16 u) {
    return __uint_as_float(((u32)u) << 16);
}
__device__ __forceinline__ u16 f2bf(float f) {          // round-to-nearest-even
    u32 u = __float_as_uint(f);
    u += 0x7FFFu + ((u >> 16) & 1u);
    return (u16)(u >> 16);
}
// rcp-based (v_rcp_f32, ~1ulp): error ~1e-7, negligible vs bf16 h rounding.
__device__ __forceinline__ float fast_sigmoid(float x) {
    return __builtin_amdgcn_rcpf(1.0f + __expf(-x));
}
__device__ __forceinline__ float fast_tanh(float x) {
    float e = __expf(-2.0f * fabsf(x));
    float t = (1.0f - e) * __builtin_amdgcn_rcpf(1.0f + e);
    return copysignf(t, x);
}

// ---------------------------------------------------------------------------
// fp32 [HIDN][ncols] tile c -> bf16 MFMA B-fragment layout [c][8 q][64 l][8].
// Fragment (c,q), lane l holds B[k = q*32 + (l>>4)*8 + j][n = c*16 + (l&15)].
// ---------------------------------------------------------------------------
__device__ __forceinline__ void wfrag_dev(
    const float* __restrict__ src, u16* __restrict__ dst, int ncols, int c,
    int t, u16 lt[HIDN][16])
{
    const float* s = src + (size_t)t * ncols + c * 16;
    #pragma unroll
    for (int j4 = 0; j4 < 4; ++j4) {
        float4 v = *(const float4*)(s + j4 * 4);
        lt[t][j4*4+0] = f2bf(v.x);
        lt[t][j4*4+1] = f2bf(v.y);
        lt[t][j4*4+2] = f2bf(v.z);
        lt[t][j4*4+3] = f2bf(v.w);
    }
    __syncthreads();
    #pragma unroll
    for (int h = 0; h < 2; ++h) {
        int f = t + h * 256;             // frag id = q*64 + l
        int q = f >> 6, l = f & 63;
        int m = l & 15, kb = q * 32 + ((l >> 4) & 3) * 8;
        u32 w[4];
        #pragma unroll
        for (int j = 0; j < 4; ++j)
            w[j] = (u32)lt[kb + 2*j][m] | ((u32)lt[kb + 2*j + 1][m] << 16);
        *(uint4*)(dst + (((size_t)c * 8 + q) * 64 + l) * 8) =
            make_uint4(w[0], w[1], w[2], w[3]);
    }
}

// ---------------------------------------------------------------------------
// wfrag for both W_lstm halves (128 blocks) — fallback-path prep.
// ---------------------------------------------------------------------------
__global__ __launch_bounds__(256) void k_wfrag2(
    const float* __restrict__ W_lstm,
    u16* __restrict__ Wxf, u16* __restrict__ Whf)
{
    __shared__ u16 lt[HIDN][16];
    const int bid = blockIdx.x;
    if (bid < 64)
        wfrag_dev(W_lstm, Wxf, GATES, bid, threadIdx.x, lt);
    else
        wfrag_dev(W_lstm + (size_t)HIDN * GATES, Whf, GATES, bid - 64,
                  threadIdx.x, lt);
}

// ---------------------------------------------------------------------------
// ALL THREE weight transforms in one launch (753 blocks) — wide-ws path.
// ---------------------------------------------------------------------------
__global__ __launch_bounds__(256) void k_wfrag3(
    const float* __restrict__ W_lstm,
    const float* __restrict__ W_dense,
    u16* __restrict__ Wxf, u16* __restrict__ Whf, u16* __restrict__ Wf)
{
    __shared__ u16 lt[HIDN][16];
    const int bid = blockIdx.x;
    if (bid < 64)
        wfrag_dev(W_lstm, Wxf, GATES, bid, threadIdx.x, lt);
    else if (bid < 128)
        wfrag_dev(W_lstm + (size_t)HIDN * GATES, Whf, GATES, bid - 64,
                  threadIdx.x, lt);
    else
        wfrag_dev(W_dense, Wf, VOCABN, bid - 128, threadIdx.x, lt);
}

// ---------------------------------------------------------------------------
// wfrag for W_dense (625 blocks) — fallback path, runs AFTER plstm (Wf
// aliases gx2 there).
// ---------------------------------------------------------------------------
__global__ __launch_bounds__(256) void k_wfrag(
    const float* __restrict__ src,   // [HIDN][ncols]
    u16*         __restrict__ dst,   // [nct][8][64][8]
    int ncols)
{
    __shared__ u16 lt[HIDN][16];
    wfrag_dev(src, dst, ncols, blockIdx.x, threadIdx.x, lt);
}

// ---------------------------------------------------------------------------
// Kernel 1 (MFMA, R3-verbatim — PASSED): gates_x packed bf16+permuted.
// 256 blocks = (t 0..63) x (rg 0..3). Output gx2 u64 layout:
//   [((t*4+rg)*4 + w')*64 + lane][slot = gg*4 + gm]
// where for gate col-tile c (= gm*16 + G, group G = c&15): w' = G>>2,
// gg = G&3. One u64 = 4 bf16 (rows kq*4+r, r=0..3). Bias folded in.
// ---------------------------------------------------------------------------
__global__ __launch_bounds__(256) void k_xgates(
    const int*   __restrict__ idx,   // [BT] = [B][T]
    const float* __restrict__ E,     // [VOCAB][HIDN]
    const u16*   __restrict__ Wxf,   // [64][8][64][8]
    const float* __restrict__ bl,    // [GATES]
    u64*         __restrict__ gx2)   // [64*4*4*64*16] u64 (8 MB)
{
    const int bid = blockIdx.x;
    const int t   = bid >> 2, rg = bid & 3;
    const int tid = threadIdx.x;
    const int w   = tid >> 6, lane = tid & 63;
    const int m   = lane & 15, quad = lane >> 4;

    v8s a[8];
    {
        const float* e = E + (size_t)idx[(rg * 16 + m) * TN + t] * HIDN
                         + quad * 8;
        #pragma unroll
        for (int q = 0; q < 8; ++q) {
            float4 x0 = *(const float4*)(e + q * 32);
            float4 x1 = *(const float4*)(e + q * 32 + 4);
            uint4 t4 = make_uint4(
                (u32)f2bf(x0.x) | ((u32)f2bf(x0.y) << 16),
                (u32)f2bf(x0.z) | ((u32)f2bf(x0.w) << 16),
                (u32)f2bf(x1.x) | ((u32)f2bf(x1.y) << 16),
                (u32)f2bf(x1.z) | ((u32)f2bf(x1.w) << 16));
            a[q] = *(v8s*)&t4;
        }
    }

    for (int i = 0; i < 16; ++i) {
        const int c = 4 * i + w;          // col-tile, c%4 == w
        v4f acc = {0.f, 0.f, 0.f, 0.f};
        #pragma unroll
        for (int q = 0; q < 8; ++q) {
            v8s b = *(const v8s*)(Wxf + (((size_t)c * 8 + q) * 64 + lane) * 8);
            acc = __builtin_amdgcn_mfma_f32_16x16x32_bf16(a[q], b, acc, 0, 0, 0);
        }
        const float bv = bl[c * 16 + m];
        u32 lo = (u32)f2bf(acc[0] + bv) | ((u32)f2bf(acc[1] + bv) << 16);
        u32 hi = (u32)f2bf(acc[2] + bv) | ((u32)f2bf(acc[3] + bv) << 16);
        u64 pk = (u64)lo | ((u64)hi << 32);
        const size_t di =
            ((((size_t)t * 4 + rg) * 4 + ((c & 15) >> 2)) * 64 + lane) * 16
            + (c & 3) * 4 + (c >> 4);
        gx2[di] = pk;
    }
}

// ---------------------------------------------------------------------------
// Kernel 2: ZERO-EXCHANGE persistent LSTM, 8-wave re-tile of the R3 kernel
// (R3 PASSED — math/layout proven; R3's perf failure was 475-reg demand vs
// the 256 arch ceiling + 1 wave/SIMD serialization).
//
// 4 blocks x 512 thr (8 waves = 2 waves/SIMD). Block rg owns 16 batch rows,
// all 256 units, zero inter-block traffic. Wave w owns unit-groups
// gA = 2w, gB = 2w+1 (group G = units G*16..+15; cts {G,16+G,32+G,48+G}).
//
// W_h per wave: 64 frags. 48 in REGISTERS (192 VGPR): gA all 4 gates + gB
// gates i,j. 16 in LDS (16 KB/wave, 128 KB total): gB gates f,o.
// Working set: rolling 1 a-frag, 8 accs, gb[8] loaded at step-top (covered
// by the MFMA phase), cs[8] -> peak ~256 regs, 2 waves/SIMD fit
// (__launch_bounds__(512,2) caps at 256).
//
// Per step: gx loads -> 8 q iters x {1 ds_read a, 2 ds_read W, 8 MFMA} ->
// 8 in-register cells (i,j,f,o of a unit land in the same lane) -> h(t) to
// LDS double buffer + Hb -> lgkmcnt(0) + s_barrier (vmem stays in flight).
// ---------------------------------------------------------------------------
__global__ __launch_bounds__(512, 2) void k_plstm(
    const u16*   __restrict__ Whf,   // [64 ct][8 q][64 l][8] h-part frags
    const u64*   __restrict__ gx2,   // packed x-gates (see k_xgates)
    u16*         __restrict__ Hb)    // [BT][HIDN] bf16 output
{
    extern __shared__ char smem[];
    u16* WgL   = (u16*)smem;                 // [8 w][2 gm2][8 q][64 l][8]
    u16* hbufu = (u16*)(smem + WLDS_B);      // [2][16][HPITCH] u16

    const int tid  = threadIdx.x;
    const int rg   = blockIdx.x;             // 0..3: batch rows rg*16..+15
    const int w    = tid >> 6;               // 0..7
    const int lane = tid & 63;
    const int m    = lane & 15, kq = lane >> 4;
    const int gA   = 2 * w, gB = 2 * w + 1;
    const int uA   = 32 * w + m;             // group A unit of this lane
    const int uB   = uA + 16;                // group B unit

    // ---- prologue: W into registers + LDS ----
    v8s wrA[4][8], wrB[2][8];
    #pragma unroll
    for (int gm = 0; gm < 4; ++gm)
        #pragma unroll
        for (int q = 0; q < 8; ++q)
            wrA[gm][q] = *(const v8s*)(
                Whf + (((size_t)(gm * 16 + gA) * 8 + q) * 64 + lane) * 8);
    #pragma unroll
    for (int gm = 0; gm < 2; ++gm)
        #pragma unroll
        for (int q = 0; q < 8; ++q)
            wrB[gm][q] = *(const v8s*)(
                Whf + (((size_t)(gm * 16 + gB) * 8 + q) * 64 + lane) * 8);
    #pragma unroll
    for (int gm2 = 0; gm2 < 2; ++gm2)
        #pragma unroll
        for (int q = 0; q < 8; ++q)
            *(uint4*)(WgL + (((w * 2 + gm2) * 8 + q) * 64 + lane) * 8) =
                *(const uint4*)(
                    Whf + (((size_t)((gm2 + 2) * 16 + gB) * 8 + q) * 64
                           + lane) * 8);

    {   // zero BOTH h buffers (t=0 reads buffer 0 as h(-1)=0); 4224 u32 total
        u32* hz = (u32*)hbufu;
        for (int i = tid; i < HBUFE; i += 512) hz[i] = 0u;
    }

    float cs[8];
    #pragma unroll
    for (int i = 0; i < 8; ++i) cs[i] = 0.0f;

    __syncthreads();

    const int sbase = 8 * (w & 1);           // gx2 slot base for this wave

    for (int t = 0; t < TN; ++t) {
        const u16* hrd = hbufu + (t & 1) * HBUFE;
        u16*       hwr = hbufu + ((t + 1) & 1) * HBUFE;

        // x-gates for THIS step: 8 u64/lane, latency covered by MFMA phase
        u64 gb[8];
        {
            const u64* gp = gx2
                + ((((size_t)t * 4 + rg) * 4 + (w >> 1)) * 64 + lane) * 16
                + sbase;
            #pragma unroll
            for (int j = 0; j < 8; ++j) gb[j] = gp[j];
        }

        v4f eA0 = {0.f,0.f,0.f,0.f}, eA1 = {0.f,0.f,0.f,0.f};
        v4f eA2 = {0.f,0.f,0.f,0.f}, eA3 = {0.f,0.f,0.f,0.f};
        v4f eB0 = {0.f,0.f,0.f,0.f}, eB1 = {0.f,0.f,0.f,0.f};
        v4f eB2 = {0.f,0.f,0.f,0.f}, eB3 = {0.f,0.f,0.f,0.f};

        const u16* abase = hrd + m * HPITCH + kq * 8;
        #pragma unroll
        for (int q = 0; q < 8; ++q) {
            v8s aq = *(const v8s*)(abase + q * 32);
            v8s b2 = *(const v8s*)(WgL + (((w * 2 + 0) * 8 + q) * 64 + lane) * 8);
            v8s b3 = *(const v8s*)(WgL + (((w * 2 + 1) * 8 + q) * 64 + lane) * 8);
            eB2 = __builtin_amdgcn_mfma_f32_16x16x32_bf16(aq, b2, eB2, 0, 0, 0);
            eB3 = __builtin_amdgcn_mfma_f32_16x16x32_bf16(aq, b3, eB3, 0, 0, 0);
            eA0 = __builtin_amdgcn_mfma_f32_16x16x32_bf16(aq, wrA[0][q], eA0, 0, 0, 0);
            eA1 = __builtin_amdgcn_mfma_f32_16x16x32_bf16(aq, wrA[1][q], eA1, 0, 0, 0);
            eA2 = __builtin_amdgcn_mfma_f32_16x16x32_bf16(aq, wrA[2][q], eA2, 0, 0, 0);
            eA3 = __builtin_amdgcn_mfma_f32_16x16x32_bf16(aq, wrA[3][q], eA3, 0, 0, 0);
            eB0 = __builtin_amdgcn_mfma_f32_16x16x32_bf16(aq, wrB[0][q], eB0, 0, 0, 0);
            eB1 = __builtin_amdgcn_mfma_f32_16x16x32_bf16(aq, wrB[1][q], eB1, 0, 0, 0);
        }

        // ---- cells: i,j,f,o of each unit live in this lane's accs ----
        const int rb = rg * 16 + kq * 4;      // top batch row of lane's quad
        #pragma unroll
        for (int r = 0; r < 4; ++r) {
            {   // group A (unit uA, cs[0..3], gb[0..3])
                float xi = bf2f((u16)(gb[0] >> (16 * r)));
                float xj = bf2f((u16)(gb[1] >> (16 * r)));
                float xf = bf2f((u16)(gb[2] >> (16 * r)));
                float xo = bf2f((u16)(gb[3] >> (16 * r)));
                float ig = fast_sigmoid(eA0[r] + xi);
                float jt = fast_tanh   (eA1[r] + xj);
                float fg = fast_sigmoid(eA2[r] + xf + 1.0f);  // forget_bias=1
                float og = fast_sigmoid(eA3[r] + xo);
                float cn = fg * cs[r] + ig * jt;
                cs[r] = cn;
                u16 hv = f2bf(og * fast_tanh(cn));
                hwr[(kq * 4 + r) * HPITCH + uA] = hv;
                Hb[((size_t)(rb + r) * TN + t) * HIDN + uA] = hv;
            }
            {   // group B (unit uB, cs[4..7], gb[4..7])
                float xi = bf2f((u16)(gb[4] >> (16 * r)));
                float xj = bf2f((u16)(gb[5] >> (16 * r)));
                float xf = bf2f((u16)(gb[6] >> (16 * r)));
                float xo = bf2f((u16)(gb[7] >> (16 * r)));
                float ig = fast_sigmoid(eB0[r] + xi);
                float jt = fast_tanh   (eB1[r] + xj);
                float fg = fast_sigmoid(eB2[r] + xf + 1.0f);
                float og = fast_sigmoid(eB3[r] + xo);
                float cn = fg * cs[4 + r] + ig * jt;
                cs[4 + r] = cn;
                u16 hv = f2bf(og * fast_tanh(cn));
                hwr[(kq * 4 + r) * HPITCH + uB] = hv;
                Hb[((size_t)(rb + r) * TN + t) * HIDN + uB] = hv;
            }
        }

        // light barrier: drain LDS ops only (Hb stores / gx loads stay in
        // flight across steps). Same pattern as R3 (HW-validated).
        asm volatile("s_waitcnt lgkmcnt(0)" ::: "memory");
        __builtin_amdgcn_s_barrier();
    }
}

// ---------------------------------------------------------------------------
// Kernel 3 (MFMA dense, 8-way vocab split — R14 verbatim): 512 blocks =
// 64 row-groups(64 rows, 4 register-resident a-frag row-tiles) x 8 vocab
// eighths (~640 KB Wf each, L2-resident per XCD under round-robin %8).
// ---------------------------------------------------------------------------
__global__ __launch_bounds__(256, 1) void k_dense(
    const u16*   __restrict__ Hb,    // [BT][HIDN] bf16
    const u16*   __restrict__ Wf,    // [625][8][64][8]
    const float* __restrict__ bd,    // [VOCAB]
    float*       __restrict__ S)     // [8][BT] partial sumexp
{
    __shared__ float Sl[64];
    const int bid = blockIdx.x;
    const int hv  = bid & 7;                    // vocab eighth (XCD-aligned)
    const int rg  = bid >> 3;                   // 0..63
    const int r0  = rg * 64;
    const int tid = threadIdx.x;
    const int w   = tid >> 6, lane = tid & 63;
    const int m   = lane & 15, kq = lane >> 4;

    if (tid < 64) Sl[tid] = 0.0f;

    v8s a[4][8];
    #pragma unroll
    for (int rt = 0; rt < 4; ++rt) {
        const u16* hrow = Hb + (size_t)(r0 + rt * 16 + m) * HIDN + kq * 8;
        #pragma unroll
        for (int q = 0; q < 8; ++q)
            a[rt][q] = *(const v8s*)(hrow + q * 32);
    }
    __syncthreads();

    float s[4][4] = {{0.f,0.f,0.f,0.f},{0.f,0.f,0.f,0.f},
                     {0.f,0.f,0.f,0.f},{0.f,0.f,0.f,0.f}};
    const int cbeg = (hv * NCT) >> 3;
    const int cend = ((hv + 1) * NCT) >> 3;
    for (int c = cbeg + w; c < cend; c += 4) {
        v4f acc[4] = {{0.f,0.f,0.f,0.f},{0.f,0.f,0.f,0.f},
                      {0.f,0.f,0.f,0.f},{0.f,0.f,0.f,0.f}};
        #pragma unroll
        for (int q = 0; q < 8; ++q) {
            v8s bq = *(const v8s*)(Wf + (((size_t)c * 8 + q) * 64 + lane) * 8);
            #pragma unroll
            for (int rt = 0; rt < 4; ++rt)
                acc[rt] = __builtin_amdgcn_mfma_f32_16x16x32_bf16(
                              a[rt][q], bq, acc[rt], 0, 0, 0);
        }
        const float bv = bd[c * 16 + m];
        #pragma unroll
        for (int rt = 0; rt < 4; ++rt)
            #pragma unroll
            for (int r = 0; r < 4; ++r)
                s[rt][r] += __expf(acc[rt][r] + bv);
    }

    #pragma unroll
    for (int rt = 0; rt < 4; ++rt)
        #pragma unroll
        for (int r = 0; r < 4; ++r)
            atomicAdd(&Sl[rt * 16 + kq * 4 + r], s[rt][r]);
    __syncthreads();
    if (tid < 64) S[(size_t)hv * BT + r0 + tid] = Sl[tid];
}

// ---------------------------------------------------------------------------
// Kernel 4 (target + final fused — R14 verbatim): per row, dot h with the
// target's W column (32 thr/row), then ppl = exp(log(sum S) - logit).
// ---------------------------------------------------------------------------
__global__ __launch_bounds__(256) void k_target(
    const u16*   __restrict__ Hb,
    const u16*   __restrict__ Wf,
    const float* __restrict__ bd,
    const int*   __restrict__ tgt,
    const float* __restrict__ S,     // [8][BT]
    float*       __restrict__ out)   // [BT]
{
    const int tid = threadIdx.x;
    const int row = blockIdx.x * 8 + (tid >> 5);
    const int t   = tid & 31;
    const int q   = t >> 2, lq = t & 3;
    const int v   = tgt[row];
    const int c   = v >> 4, vm = v & 15;
    const int kb  = q * 32 + lq * 8;

    v8s h  = *(const v8s*)(Hb + (size_t)row * HIDN + kb);
    v8s wv = *(const v8s*)(Wf + (((size_t)c * 8 + q) * 64 + lq * 16 + vm) * 8);
    float acc = 0.0f;
    #pragma unroll
    for (int j = 0; j < 8; ++j)
        acc = fmaf(bf2f((u16)h[j]), bf2f((u16)wv[j]), acc);
    #pragma unroll
    for (int off = 16; off >= 1; off >>= 1)
        acc += __shfl_down(acc, off, 32);
    if (t == 0) {
        float tlv = acc + bd[v];
        float sum = 0.0f;
        #pragma unroll
        for (int p = 0; p < 8; ++p) sum += S[(size_t)p * BT + row];
        out[row] = __expf(__logf(sum) - tlv);
    }
}

// ---------------------------------------------------------------------------
extern "C" void kernel_launch(void* const* d_in, const int* in_sizes, int n_in,
                              void* d_out, int out_size, void* d_ws, size_t ws_size,
                              hipStream_t stream) {
    const int*   input   = (const int*)  d_in[0];   // [B,T]
    const int*   targets = (const int*)  d_in[1];   // [B,T]
    const float* E       = (const float*)d_in[2];   // [VOCAB,HID]
    const float* W_lstm  = (const float*)d_in[3];   // [2H,4H]
    const float* b_lstm  = (const float*)d_in[4];   // [4H]
    const float* W_dense = (const float*)d_in[5];   // [HID,VOCAB]
    const float* b_dense = (const float*)d_in[6];   // [VOCAB]
    float* out = (float*)d_out;                     // [B,T] perplexity

    static bool attr_done = false;
    if (!attr_done) {
        hipFuncSetAttribute((const void*)k_plstm,
                            hipFuncAttributeMaxDynamicSharedMemorySize,
                            SMEMSZ);
        attr_done = true;
    }

    char* ws = (char*)d_ws;
    const bool wide = (ws_size >= ((size_t)25 << 20));

    if (wide) {
        // 5-node layout:
        //  [0,8M): gx2 | [16M,21.12M): Wf | [21.25M,23.25M): Hb
        //  [23.25M,+512K): Whf | [23.75M,+512K): Wxf
        //  [24.25M+128K,+128K): S
        u64*   gx2 = (u64*)ws;
        u16*   Wf  = (u16*)(ws + ((size_t)16 << 20));
        u16*   Hb  = (u16*)(ws + ((size_t)21 << 20) + ((size_t)256 << 10));
        u16*   Whf = (u16*)(ws + ((size_t)23 << 20) + ((size_t)256 << 10));
        u16*   Wxf = (u16*)(ws + ((size_t)23 << 20) + ((size_t)768 << 10));
        float* S   = (float*)(ws + ((size_t)24 << 20) + ((size_t)384 << 10));

        k_wfrag3<<<753,     256, 0, stream>>>(W_lstm, W_dense, Wxf, Whf, Wf);
        k_xgates<<<BT / 16, 256, 0, stream>>>(input, E, Wxf, b_lstm, gx2);
        k_plstm <<<4,       512, SMEMSZ, stream>>>(Whf, gx2, Hb);
        k_dense <<<512,     256, 0, stream>>>(Hb, Wf, b_dense, S);
        k_target<<<BT / 8,  256, 0, stream>>>(Hb, Wf, b_dense, targets, S, out);
    } else {
        // 6-node fallback (Wf aliases gx2 after plstm).
        //  [0,8M): gx2/Wf | [16M,18M): Hb | [18M,+512K): Whf
        //  [18.5M,+512K): Wxf | [19M+128K,+128K): S
        u64*   gx2 = (u64*)ws;
        u16*   Wf  = (u16*)ws;
        u16*   Hb  = (u16*)(ws + ((size_t)16 << 20));
        u16*   Whf = (u16*)(ws + ((size_t)18 << 20));
        u16*   Wxf = (u16*)(ws + ((size_t)18 << 20) + ((size_t)512 << 10));
        float* S   = (float*)(ws + ((size_t)19 << 20) + ((size_t)128 << 10));

        k_wfrag2<<<128,     256, 0, stream>>>(W_lstm, Wxf, Whf);
        k_xgates<<<BT / 16, 256, 0, stream>>>(input, E, Wxf, b_lstm, gx2);
        k_plstm <<<4,       512, SMEMSZ, stream>>>(Whf, gx2, Hb);
        k_wfrag <<<NCT,     256, 0, stream>>>(W_dense, Wf, VOCABN);
        k_dense <<<512,     256, 0, stream>>>(Hb, Wf, b_dense, S);
        k_target<<<BT / 8,  256, 0, stream>>>(Hb, Wf, b_dense, targets, S, out);
    }
}